// Round 2
// baseline (202.216 us; speedup 1.0000x reference)
//
#include <hip/hip_runtime.h>

// Regime-switching Kalman filter, structure-exploiting scalar form.
// One thread per series; 64-thread blocks (= 1 wave) stage y through LDS in
// 8-timestep chunks with a register-held prefetch of the next chunk.

static __device__ __forceinline__ float frcp(float x) { return __builtin_amdgcn_rcpf(x); }

#define NLOG2PI    16.540893597684108f   // 9*log(2*pi)
#define LOG_1M_P22 -9.210330372026184f   // log(1 - 0.9999 + 1e-9)
#define LOG_P22    -1.00004000233e-4f    // log(0.9999 + 1e-9)
#define EPSF       1e-9f
#define LOG_EPS    -20.72326583694641f   // log(1e-9)

#define TCHUNK 8                         // timesteps per LDS chunk
#define CF     (TCHUNK * 9)              // 72 floats per series per chunk
#define LSTRIDE 76                       // LDS row stride (16B-aligned float4 stores)

__global__ __launch_bounds__(64)
void kf_kernel(const float* __restrict__ y,      // y[n][t][o], row = Nt*9 floats
               const float* __restrict__ pBG, const float* __restrict__ pBT,
               const float* __restrict__ pBB, const float* __restrict__ pBW,
               const float* __restrict__ lam1, const float* __restrict__ lam2,
               const float* __restrict__ qd,  const float* __restrict__ rd,
               const float* __restrict__ pG1, const float* __restrict__ pG2,
               float* __restrict__ out, int N, int Nt)
{
    __shared__ float lds[64 * LSTRIDE];
    const int lane = threadIdx.x;
    const int n0 = blockIdx.x * 64;
    const int n = n0 + lane;
    const bool valid = (n < N);
    const int rowlen = Nt * 9;
    const int nchunk = Nt / TCHUNK;

    // ---- wave-uniform setup ----
    const float bg = pBG[0], bt = pBT[0], bb = pBB[0], bw = pBW[0];
    float a[9], l2v[9], id[9], ad[9], ld[9];
    a[0] = 1.f; a[1] = lam1[0]; a[2] = lam1[1];
    a[3] = 1.f; a[4] = lam1[2]; a[5] = lam1[3];
    a[6] = 1.f; a[7] = lam1[4]; a[8] = lam1[5];
    l2v[0] = 1.f;
    #pragma unroll
    for (int i = 0; i < 8; ++i) l2v[i + 1] = lam2[i];
    float logdetD = 0.f;
    #pragma unroll
    for (int o = 0; o < 9; ++o) {
        float dv = fabsf(rd[o]) + 1.0e-4f + 1.0e-5f;  // R diag + jitter
        id[o] = 1.0f / dv;
        ad[o] = a[o] * id[o];
        ld[o] = l2v[o] * id[o];
        logdetD += __logf(dv);
    }
    const float q0 = fabsf(qd[0]) + 1e-4f, q1 = fabsf(qd[1]) + 1e-4f;
    const float q2 = fabsf(qd[2]) + 1e-4f, q3 = fabsf(qd[3]) + 1e-4f;
    const float g0 = a[0]*ad[0] + a[1]*ad[1] + a[2]*ad[2];   // A^T D^-1 A (diagonal)
    const float g1 = a[3]*ad[3] + a[4]*ad[4] + a[5]*ad[5];
    const float g2 = a[6]*ad[6] + a[7]*ad[7] + a[8]*ad[8];
    float h = 0.f;
    #pragma unroll
    for (int o = 0; o < 9; ++o) h += l2v[o] * ld[o];         // l2^T D^-1 l2
    // branch-12 constants (prior N(0, diag(q0..q2)))
    const float pk0 = q0 / (1.f + q0 * g0);
    const float pk1 = q1 / (1.f + q1 * g1);
    const float pk2 = q2 / (1.f + q2 * g2);
    const float logdet12 = logdetD + __logf((1.f + q0*g0) * (1.f + q1*g1) * (1.f + q2*g2));
    const float gam1 = pG1[0], w0 = pG2[0], w1 = pG2[1], w2 = pG2[2];

    // ---- state ----
    float pr1 = 0.99f, pr2 = 0.01f;
    float se0 = 0.f, se1 = 0.f, se2 = 0.f;
    float P00 = 1000.f, P01 = 0.f, P02 = 0.f, P11 = 1000.f, P12 = 0.f, P22 = 1000.f;
    float sm2 = 0.f, sp2 = 1e-9f;
    float acc = 0.0f;

    // ---- chunked coalesced staging: flat float4 index f = i*64+lane over 64x18 ----
    const float* yb = y + (size_t)n0 * rowlen;
    int grow[18], gcol[18];
    #pragma unroll
    for (int i = 0; i < 18; ++i) {
        int f = i * 64 + lane;
        grow[i] = f / 18;
        gcol[i] = f - grow[i] * 18;
    }
    float4 buf[18];
    #pragma unroll
    for (int i = 0; i < 18; ++i)
        if (n0 + grow[i] < N)
            buf[i] = *(const float4*)(yb + (size_t)grow[i] * rowlen + gcol[i] * 4);

    for (int c = 0; c < nchunk; ++c) {
        __syncthreads();   // WAR: previous chunk's reads done
        #pragma unroll
        for (int i = 0; i < 18; ++i)
            *(float4*)&lds[grow[i] * LSTRIDE + gcol[i] * 4] = buf[i];
        __syncthreads();
        if (c + 1 < nchunk) {
            const int cofs = (c + 1) * CF;
            #pragma unroll
            for (int i = 0; i < 18; ++i)
                if (n0 + grow[i] < N)
                    buf[i] = *(const float4*)(yb + (size_t)grow[i] * rowlen + cofs + gcol[i] * 4);
        }

        #pragma unroll
        for (int s = 0; s < TCHUNK; ++s) {
            float yv[9];
            #pragma unroll
            for (int o = 0; o < 9; ++o) yv[o] = lds[lane * LSTRIDE + s * 9 + o];

            // HMM transition: stable log-sigmoid, clamped to match +1e-9 floor
            float logit = gam1 + w0 * se0 + w1 * se1 + w2 * se2;
            float alog = fabsf(logit);
            float lse = __logf(1.0f + __expf(-alog));
            float lp11 = fmaxf(fminf(logit, 0.0f) - lse, LOG_EPS);   // log(p11+eps)
            float lm11 = fmaxf(fminf(-logit, 0.0f) - lse, LOG_EPS);  // log(1-p11+eps)

            // ---------- branch 11 (regime1 -> regime1), rank-3 Woodbury ----------
            float ep0 = bg * se0, ep1 = bt * se1, ep2 = bb * se2;
            float S00 = bg*bg*P00 + q0, S01 = bg*bt*P01, S02 = bg*bb*P02;
            float S11 = bt*bt*P11 + q1, S12 = bt*bb*P12, S22 = bb*bb*P22 + q2;
            float v0 = yv[0] - a[0]*ep0, v1 = yv[1] - a[1]*ep0, v2 = yv[2] - a[2]*ep0;
            float v3 = yv[3] - a[3]*ep1, v4 = yv[4] - a[4]*ep1, v5 = yv[5] - a[5]*ep1;
            float v6 = yv[6] - a[6]*ep2, v7 = yv[7] - a[7]*ep2, v8 = yv[8] - a[8]*ep2;
            float u0 = ad[0]*v0 + ad[1]*v1 + ad[2]*v2;
            float u1 = ad[3]*v3 + ad[4]*v4 + ad[5]*v5;
            float u2 = ad[6]*v6 + ad[7]*v7 + ad[8]*v8;
            float vdv = id[0]*v0*v0 + id[1]*v1*v1 + id[2]*v2*v2
                      + id[3]*v3*v3 + id[4]*v4*v4 + id[5]*v5*v5
                      + id[6]*v6*v6 + id[7]*v7*v7 + id[8]*v8*v8;
            float cA = S11*S22 - S12*S12, cB = S02*S12 - S01*S22, cC = S01*S12 - S02*S11;
            float detS = S00*cA + S01*cB + S02*cC;
            float cD = S00*S22 - S02*S02, cE = S01*S02 - S00*S12, cF = S00*S11 - S01*S01;
            float iS = frcp(detS);
            float C00 = cA*iS + g0, C01 = cB*iS, C02 = cC*iS;
            float C11 = cD*iS + g1, C12 = cE*iS, C22 = cF*iS + g2;
            float eA = C11*C22 - C12*C12, eB = C02*C12 - C01*C22, eC = C01*C12 - C02*C11;
            float detC = C00*eA + C01*eB + C02*eC;
            float eD = C00*C22 - C02*C02, eE = C01*C02 - C00*C12, eF = C00*C11 - C01*C01;
            float iC = frcp(detC);
            float Ci00 = eA*iC, Ci01 = eB*iC, Ci02 = eC*iC;
            float Ci11 = eD*iC, Ci12 = eE*iC, Ci22 = eF*iC;
            float t0 = Ci00*u0 + Ci01*u1 + Ci02*u2;
            float t1 = Ci01*u0 + Ci11*u1 + Ci12*u2;
            float t2 = Ci02*u0 + Ci12*u1 + Ci22*u2;
            float quad11 = vdv - (u0*t0 + u1*t1 + u2*t2);
            float ll11 = -0.5f * (quad11 + logdetD + __logf(detS * detC) + NLOG2PI);
            float eu0 = ep0 + t0, eu1 = ep1 + t1, eu2 = ep2 + t2;

            // ---------- branch 12 (regime2 -> regime1), constant prior ----------
            float u120 = u0 + g0*ep0, u121 = u1 + g1*ep1, u122 = u2 + g2*ep2;
            float ydy = vdv + 2.f*(ep0*u0 + ep1*u1 + ep2*u2)
                      + g0*ep0*ep0 + g1*ep1*ep1 + g2*ep2*ep2;
            float quad12 = ydy - (pk0*u120*u120 + pk1*u121*u121 + pk2*u122*u122);
            float ll12 = -0.5f * (quad12 + logdet12 + NLOG2PI);
            float f0 = pk0*u120, f1 = pk1*u121, f2 = pk2*u122;

            // ---------- branches 21/22 (-> regime2), rank-1 Sherman-Morrison ----------
            float yl = ld[0]*yv[0] + ld[1]*yv[1] + ld[2]*yv[2] + ld[3]*yv[3] + ld[4]*yv[4]
                     + ld[5]*yv[5] + ld[6]*yv[6] + ld[7]*yv[7] + ld[8]*yv[8];
            float m21 = (se0 + se1 + se2) * (1.0f / 3.0f);
            float sP = P00 + P11 + P22 + 2.f*(P01 + P02 + P12);
            float pa = q3 + (1.0f / 9.0f) * sP;
            float m22 = bw * sm2;
            float pb = bw*bw*sp2 + q3;
            float u1a = yl - m21*h;
            float vda = ydy - m21*(2.f*yl - m21*h);
            float dena = 1.f + pa*h;  float idea = frcp(dena);
            float quad21 = vda - pa*u1a*u1a*idea;
            float ll21 = -0.5f * (quad21 + logdetD + __logf(dena) + NLOG2PI);
            float pua = pa*idea;
            float eua = m21 + pua*u1a;
            float u1b = yl - m22*h;
            float vdb = ydy - m22*(2.f*yl - m22*h);
            float denb = 1.f + pb*h;  float ideb = frcp(denb);
            float quad22 = vdb - pb*u1b*u1b*ideb;
            float ll22 = -0.5f * (quad22 + logdetD + __logf(denb) + NLOG2PI);
            float pub = pb*ideb;
            float eub = m22 + pub*u1b;

            // ---------- mixing ----------
            float lp1 = __logf(pr1 + EPSF), lp2 = __logf(pr2 + EPSF);
            float c11 = lp1 + lp11 + ll11;
            float c21 = lp1 + lm11 + ll21;
            float c12 = lp2 + LOG_1M_P22 + ll12;
            float c22 = lp2 + LOG_P22 + ll22;
            float mx = fmaxf(fmaxf(c11, c12), fmaxf(c21, c22));
            float s11 = __expf(c11 - mx), s12 = __expf(c12 - mx);
            float s21 = __expf(c21 - mx), s22 = __expf(c22 - mx);
            float ssum = s11 + s12 + s21 + s22;
            acc += mx + __logf(ssum);
            float pr1n = s11 + s12, pr2n = s21 + s22;
            float inv1 = frcp(pr1n + EPSF * ssum);
            float W11 = s11 * inv1, W12 = s12 * inv1;
            float inv2 = frcp(pr2n + EPSF * ssum);
            float W21 = s21 * inv2, W22 = s22 * inv2;
            float issum = frcp(ssum);
            pr1 = pr1n * issum; pr2 = pr2n * issum;

            // ---------- collapse regime 1 (3x3) ----------
            float ne0 = W11*eu0 + W12*f0;
            float ne1 = W11*eu1 + W12*f1;
            float ne2 = W11*eu2 + W12*f2;
            float da0 = eu0 - ne0, da1 = eu1 - ne1, da2 = eu2 - ne2;
            float db0 = f0 - ne0,  db1 = f1 - ne1,  db2 = f2 - ne2;
            P00 = W11*(Ci00 + da0*da0) + W12*(pk0 + db0*db0);
            P01 = W11*(Ci01 + da0*da1) + W12*(db0*db1);
            P02 = W11*(Ci02 + da0*da2) + W12*(db0*db2);
            P11 = W11*(Ci11 + da1*da1) + W12*(pk1 + db1*db1);
            P12 = W11*(Ci12 + da1*da2) + W12*(db1*db2);
            P22 = W11*(Ci22 + da2*da2) + W12*(pk2 + db2*db2);
            se0 = ne0; se1 = ne1; se2 = ne2;

            // ---------- collapse regime 2 (scalar) ----------
            float nm2 = W21*eua + W22*eub;
            float dc = eua - nm2, dd = eub - nm2;
            sp2 = W21*(pua + dc*dc) + W22*(pub + dd*dd);
            sm2 = nm2;
        }
    }

    if (!valid) acc = 0.0f;
    #pragma unroll
    for (int off = 32; off; off >>= 1) acc += __shfl_down(acc, off, 64);
    if (threadIdx.x == 0) atomicAdd(out, acc);
}

extern "C" void kernel_launch(void* const* d_in, const int* in_sizes, int n_in,
                              void* d_out, int out_size, void* d_ws, size_t ws_size,
                              hipStream_t stream)
{
    const float* y    = (const float*)d_in[0];
    const float* pBG  = (const float*)d_in[1];
    const float* pBT  = (const float*)d_in[2];
    const float* pBB  = (const float*)d_in[3];
    const float* pBW  = (const float*)d_in[4];
    const float* lam1 = (const float*)d_in[5];
    const float* lam2 = (const float*)d_in[6];
    const float* qd   = (const float*)d_in[7];
    const float* rd   = (const float*)d_in[8];
    const float* pG1  = (const float*)d_in[9];
    const float* pG2  = (const float*)d_in[10];

    const int total = in_sizes[0];
    const int Nt = 64, O = 9;
    const int N = total / (Nt * O);

    hipMemsetAsync(d_out, 0, sizeof(float) * (size_t)out_size, stream);

    const int blocks = (N + 63) / 64;
    kf_kernel<<<blocks, 64, 0, stream>>>(y, pBG, pBT, pBB, pBW, lam1, lam2,
                                         qd, rd, pG1, pG2, (float*)d_out, N, Nt);
}

// Round 3
// 144.629 us; speedup vs baseline: 1.3982x; 1.3982x over previous
//
#include <hip/hip_runtime.h>

// Regime-switching Kalman filter, structure-exploiting scalar form.
// One thread per series. Each thread's y-row is contiguous (Nt*9=576 floats);
// we stage 4-step chunks (9 float4) into a register double-buffer with
// fully-static indexing (no LDS, no scratch). Block partial sums -> d_ws,
// tiny reducer kernel -> d_out (no memset, no global atomics).

static __device__ __forceinline__ float frcp(float x) { return __builtin_amdgcn_rcpf(x); }

#define NLOG2PI    16.540893597684108f   // 9*log(2*pi)
#define LOG_1M_P22 -9.210330372026184f   // log(1 - 0.9999 + 1e-9)
#define LOG_P22    -1.00004000233e-4f    // log(0.9999 + 1e-9)
#define EPSF       1e-9f
#define LOG_EPS    -20.72326583694641f   // log(1e-9)

__global__ __launch_bounds__(64)
void kf_kernel(const float* __restrict__ y,      // y[n][t][o]
               const float* __restrict__ pBG, const float* __restrict__ pBT,
               const float* __restrict__ pBB, const float* __restrict__ pBW,
               const float* __restrict__ lam1, const float* __restrict__ lam2,
               const float* __restrict__ qd,  const float* __restrict__ rd,
               const float* __restrict__ pG1, const float* __restrict__ pG2,
               float* __restrict__ partial, int N, int Nt)
{
    const int lane = threadIdx.x;
    const int n = blockIdx.x * 64 + lane;
    const bool valid = (n < N);
    const int rowlen = Nt * 9;          // 576
    const int nchunk = Nt / 4;          // 16 chunks of 4 steps (36 floats = 9 float4)

    // ---- setup (wave-uniform scalars) ----
    const float bg = pBG[0], bt = pBT[0], bb = pBB[0], bw = pBW[0];
    float a[9], l2v[9], id[9], ad[9], ld[9];
    a[0] = 1.f; a[1] = lam1[0]; a[2] = lam1[1];
    a[3] = 1.f; a[4] = lam1[2]; a[5] = lam1[3];
    a[6] = 1.f; a[7] = lam1[4]; a[8] = lam1[5];
    l2v[0] = 1.f;
    #pragma unroll
    for (int i = 0; i < 8; ++i) l2v[i + 1] = lam2[i];
    float logdetD = 0.f;
    #pragma unroll
    for (int o = 0; o < 9; ++o) {
        float dv = fabsf(rd[o]) + 1.0e-4f + 1.0e-5f;  // R diag + jitter
        id[o] = 1.0f / dv;
        ad[o] = a[o] * id[o];
        ld[o] = l2v[o] * id[o];
        logdetD += __logf(dv);
    }
    const float q0 = fabsf(qd[0]) + 1e-4f, q1 = fabsf(qd[1]) + 1e-4f;
    const float q2 = fabsf(qd[2]) + 1e-4f, q3 = fabsf(qd[3]) + 1e-4f;
    const float g0 = a[0]*ad[0] + a[1]*ad[1] + a[2]*ad[2];   // A^T D^-1 A (diag)
    const float g1 = a[3]*ad[3] + a[4]*ad[4] + a[5]*ad[5];
    const float g2 = a[6]*ad[6] + a[7]*ad[7] + a[8]*ad[8];
    float h = 0.f;
    #pragma unroll
    for (int o = 0; o < 9; ++o) h += l2v[o] * ld[o];         // l2^T D^-1 l2
    const float pk0 = q0 / (1.f + q0 * g0);
    const float pk1 = q1 / (1.f + q1 * g1);
    const float pk2 = q2 / (1.f + q2 * g2);
    const float logdet12 = logdetD + __logf((1.f + q0*g0) * (1.f + q1*g1) * (1.f + q2*g2));
    const float gam1 = pG1[0], w0 = pG2[0], w1 = pG2[1], w2 = pG2[2];

    // ---- state ----
    float lp1 = -0.010050326f;           // log(0.99 + 1e-9)
    float lp2 = -4.6051702f;             // log(0.01 + 1e-9)
    float se0 = 0.f, se1 = 0.f, se2 = 0.f;
    float P00 = 1000.f, P01 = 0.f, P02 = 0.f, P11 = 1000.f, P12 = 0.f, P22 = 1000.f;
    float sm2 = 0.f, sp2 = 1e-9f;
    float acc = 0.0f;

    const float* row = y + (size_t)(valid ? n : 0) * rowlen;

    float4 A[9], B[9];
    #pragma unroll
    for (int i = 0; i < 9; ++i) A[i] = *(const float4*)(row + i * 4);

    auto step4 = [&](const float4 (&buf)[9]) {
        #pragma unroll
        for (int s = 0; s < 4; ++s) {
            float yv[9];
            #pragma unroll
            for (int o = 0; o < 9; ++o) {
                const int idx = s * 9 + o, vno = idx >> 2, cm = idx & 3;
                yv[o] = (cm == 0) ? buf[vno].x : (cm == 1) ? buf[vno].y
                      : (cm == 2) ? buf[vno].z : buf[vno].w;
            }

            // HMM transition: stable log-sigmoid, clamped to match +1e-9 floor
            float logit = gam1 + w0 * se0 + w1 * se1 + w2 * se2;
            float alog = fabsf(logit);
            float lse = __logf(1.0f + __expf(-alog));
            float lp11 = fmaxf(fminf(logit, 0.0f) - lse, LOG_EPS);
            float lm11 = fmaxf(fminf(-logit, 0.0f) - lse, LOG_EPS);

            // ---------- branch 11 (regime1 -> regime1), rank-3 Woodbury ----------
            float ep0 = bg * se0, ep1 = bt * se1, ep2 = bb * se2;
            float S00 = bg*bg*P00 + q0, S01 = bg*bt*P01, S02 = bg*bb*P02;
            float S11 = bt*bt*P11 + q1, S12 = bt*bb*P12, S22 = bb*bb*P22 + q2;
            float v0 = yv[0] - a[0]*ep0, v1 = yv[1] - a[1]*ep0, v2 = yv[2] - a[2]*ep0;
            float v3 = yv[3] - a[3]*ep1, v4 = yv[4] - a[4]*ep1, v5 = yv[5] - a[5]*ep1;
            float v6 = yv[6] - a[6]*ep2, v7 = yv[7] - a[7]*ep2, v8 = yv[8] - a[8]*ep2;
            float u0 = ad[0]*v0 + ad[1]*v1 + ad[2]*v2;
            float u1 = ad[3]*v3 + ad[4]*v4 + ad[5]*v5;
            float u2 = ad[6]*v6 + ad[7]*v7 + ad[8]*v8;
            float vdv = id[0]*v0*v0 + id[1]*v1*v1 + id[2]*v2*v2
                      + id[3]*v3*v3 + id[4]*v4*v4 + id[5]*v5*v5
                      + id[6]*v6*v6 + id[7]*v7*v7 + id[8]*v8*v8;
            float cA = S11*S22 - S12*S12, cB = S02*S12 - S01*S22, cC = S01*S12 - S02*S11;
            float detS = S00*cA + S01*cB + S02*cC;
            float cD = S00*S22 - S02*S02, cE = S01*S02 - S00*S12, cF = S00*S11 - S01*S01;
            float iS = frcp(detS);
            float C00 = cA*iS + g0, C01 = cB*iS, C02 = cC*iS;
            float C11 = cD*iS + g1, C12 = cE*iS, C22 = cF*iS + g2;
            float eA = C11*C22 - C12*C12, eB = C02*C12 - C01*C22, eC = C01*C12 - C02*C11;
            float detC = C00*eA + C01*eB + C02*eC;
            float eD = C00*C22 - C02*C02, eE = C01*C02 - C00*C12, eF = C00*C11 - C01*C01;
            float iC = frcp(detC);
            float Ci00 = eA*iC, Ci01 = eB*iC, Ci02 = eC*iC;
            float Ci11 = eD*iC, Ci12 = eE*iC, Ci22 = eF*iC;
            float t0 = Ci00*u0 + Ci01*u1 + Ci02*u2;
            float t1 = Ci01*u0 + Ci11*u1 + Ci12*u2;
            float t2 = Ci02*u0 + Ci12*u1 + Ci22*u2;
            float quad11 = vdv - (u0*t0 + u1*t1 + u2*t2);
            float ll11 = -0.5f * (quad11 + logdetD + __logf(detS * detC) + NLOG2PI);
            float eu0 = ep0 + t0, eu1 = ep1 + t1, eu2 = ep2 + t2;

            // ---------- branch 12 (regime2 -> regime1), constant prior ----------
            float u120 = u0 + g0*ep0, u121 = u1 + g1*ep1, u122 = u2 + g2*ep2;
            float ydy = vdv + 2.f*(ep0*u0 + ep1*u1 + ep2*u2)
                      + g0*ep0*ep0 + g1*ep1*ep1 + g2*ep2*ep2;
            float quad12 = ydy - (pk0*u120*u120 + pk1*u121*u121 + pk2*u122*u122);
            float ll12 = -0.5f * (quad12 + logdet12 + NLOG2PI);
            float f0 = pk0*u120, f1 = pk1*u121, f2 = pk2*u122;

            // ---------- branches 21/22 (-> regime2), rank-1 Sherman-Morrison ----------
            float yl = ld[0]*yv[0] + ld[1]*yv[1] + ld[2]*yv[2] + ld[3]*yv[3] + ld[4]*yv[4]
                     + ld[5]*yv[5] + ld[6]*yv[6] + ld[7]*yv[7] + ld[8]*yv[8];
            float m21 = (se0 + se1 + se2) * (1.0f / 3.0f);
            float sP = P00 + P11 + P22 + 2.f*(P01 + P02 + P12);
            float pa = q3 + (1.0f / 9.0f) * sP;
            float m22 = bw * sm2;
            float pb = bw*bw*sp2 + q3;
            float u1a = yl - m21*h;
            float vda = ydy - m21*(2.f*yl - m21*h);
            float dena = 1.f + pa*h;  float idea = frcp(dena);
            float quad21 = vda - pa*u1a*u1a*idea;
            float ll21 = -0.5f * (quad21 + logdetD + __logf(dena) + NLOG2PI);
            float pua = pa*idea;
            float eua = m21 + pua*u1a;
            float u1b = yl - m22*h;
            float vdb = ydy - m22*(2.f*yl - m22*h);
            float denb = 1.f + pb*h;  float ideb = frcp(denb);
            float quad22 = vdb - pb*u1b*u1b*ideb;
            float ll22 = -0.5f * (quad22 + logdetD + __logf(denb) + NLOG2PI);
            float pub = pb*ideb;
            float eub = m22 + pub*u1b;

            // ---------- mixing ----------
            float c11 = lp1 + lp11 + ll11;
            float c21 = lp1 + lm11 + ll21;
            float c12 = lp2 + LOG_1M_P22 + ll12;
            float c22 = lp2 + LOG_P22 + ll22;
            float mx = fmaxf(fmaxf(c11, c12), fmaxf(c21, c22));
            float s11 = __expf(c11 - mx), s12 = __expf(c12 - mx);
            float s21 = __expf(c21 - mx), s22 = __expf(c22 - mx);
            float ssum = s11 + s12 + s21 + s22;
            float lss = __logf(ssum);
            acc += mx + lss;
            float pr1n = s11 + s12, pr2n = s21 + s22;
            float den1 = pr1n + EPSF * ssum;
            float den2 = pr2n + EPSF * ssum;
            float inv1 = frcp(den1);
            float inv2 = frcp(den2);
            float W11 = s11 * inv1, W12 = s12 * inv1;
            float W21 = s21 * inv2, W22 = s22 * inv2;
            lp1 = __logf(den1) - lss;            // log(prob1 + eps) for next step
            lp2 = __logf(den2) - lss;

            // ---------- collapse regime 1 (3x3) ----------
            float ne0 = W11*eu0 + W12*f0;
            float ne1 = W11*eu1 + W12*f1;
            float ne2 = W11*eu2 + W12*f2;
            float da0 = eu0 - ne0, da1 = eu1 - ne1, da2 = eu2 - ne2;
            float db0 = f0 - ne0,  db1 = f1 - ne1,  db2 = f2 - ne2;
            P00 = W11*(Ci00 + da0*da0) + W12*(pk0 + db0*db0);
            P01 = W11*(Ci01 + da0*da1) + W12*(db0*db1);
            P02 = W11*(Ci02 + da0*da2) + W12*(db0*db2);
            P11 = W11*(Ci11 + da1*da1) + W12*(pk1 + db1*db1);
            P12 = W11*(Ci12 + da1*da2) + W12*(db1*db2);
            P22 = W11*(Ci22 + da2*da2) + W12*(pk2 + db2*db2);
            se0 = ne0; se1 = ne1; se2 = ne2;

            // ---------- collapse regime 2 (scalar) ----------
            float nm2 = W21*eua + W22*eub;
            float dc = eua - nm2, dd = eub - nm2;
            sp2 = W21*(pua + dc*dc) + W22*(pub + dd*dd);
            sm2 = nm2;
        }
    };

    // chunk pairs: compute A(c), prefetch A<-c+2; compute B(c+1), prefetch B<-c+3
    for (int c = 0; c < nchunk; c += 2) {
        {   // prefetch chunk c+1 into B (clamped; redundant re-load at the tail)
            const float* p = row + min(c + 1, nchunk - 1) * 36;
            #pragma unroll
            for (int i = 0; i < 9; ++i) B[i] = *(const float4*)(p + i * 4);
        }
        step4(A);
        {   // prefetch chunk c+2 into A
            const float* p = row + min(c + 2, nchunk - 1) * 36;
            #pragma unroll
            for (int i = 0; i < 9; ++i) A[i] = *(const float4*)(p + i * 4);
        }
        step4(B);
    }

    if (!valid) acc = 0.0f;
    #pragma unroll
    for (int off = 32; off; off >>= 1) acc += __shfl_down(acc, off, 64);
    if (lane == 0) partial[blockIdx.x] = acc;
}

__global__ __launch_bounds__(64)
void reduce_k(const float* __restrict__ part, float* __restrict__ out, int nb)
{
    float s = 0.f;
    for (int i = threadIdx.x; i < nb; i += 64) s += part[i];
    #pragma unroll
    for (int off = 32; off; off >>= 1) s += __shfl_down(s, off, 64);
    if (threadIdx.x == 0) out[0] = s;
}

extern "C" void kernel_launch(void* const* d_in, const int* in_sizes, int n_in,
                              void* d_out, int out_size, void* d_ws, size_t ws_size,
                              hipStream_t stream)
{
    const float* y    = (const float*)d_in[0];
    const float* pBG  = (const float*)d_in[1];
    const float* pBT  = (const float*)d_in[2];
    const float* pBB  = (const float*)d_in[3];
    const float* pBW  = (const float*)d_in[4];
    const float* lam1 = (const float*)d_in[5];
    const float* lam2 = (const float*)d_in[6];
    const float* qd   = (const float*)d_in[7];
    const float* rd   = (const float*)d_in[8];
    const float* pG1  = (const float*)d_in[9];
    const float* pG2  = (const float*)d_in[10];

    const int total = in_sizes[0];
    const int Nt = 64, O = 9;
    const int N = total / (Nt * O);
    const int blocks = (N + 63) / 64;

    float* partial = (float*)d_ws;
    kf_kernel<<<blocks, 64, 0, stream>>>(y, pBG, pBT, pBB, pBW, lam1, lam2,
                                         qd, rd, pG1, pG2, partial, N, Nt);
    reduce_k<<<1, 64, 0, stream>>>(partial, (float*)d_out, blocks);
}

// Round 5
// 138.712 us; speedup vs baseline: 1.4578x; 1.0427x over previous
//
#include <hip/hip_runtime.h>

// Regime-switching Kalman filter, structure-exploiting scalar form.
// One thread per series; register double-buffered 4-step chunks (9 float4).
// __launch_bounds__(64,1): grid is 256 waves on 256 CUs (1 wave/SIMD), so
// occupancy is grid-limited anyway -> give the compiler the full 512-VGPR
// budget so the prefetch buffers stay live and loads hoist a chunk ahead.
// All transcendentals in native base-2 (raw GCN builtins: v_exp_f32/v_log_f32
// are 2^x / log2 x; the glibc-colliding __exp2f/__log2f names are avoided).
// Mixing done in scaled-linear domain (algebraically equal to the reference's
// log-domain form incl. EPS terms).

static __device__ __forceinline__ float frcp(float x)  { return __builtin_amdgcn_rcpf(x); }
static __device__ __forceinline__ float fexp2(float x) { return __builtin_amdgcn_exp2f(x); }
static __device__ __forceinline__ float flog2(float x) { return __builtin_amdgcn_logf(x); }

#define EPSF   1e-9f
#define L2E    1.4426950408889634f    // log2(e)
#define LN2    0.6931471805599453f
#define L2_2PI_9 23.86346461225016f   // 9*log2(2*pi)
#define C12F   1.00001e-4f            // (1 - 0.9999) + 1e-9, linear prior factor
#define P22F   0.99990001f            // 0.9999 + 1e-9

__global__ __launch_bounds__(64, 1)
void kf_kernel(const float* __restrict__ y,      // y[n][t][o]
               const float* __restrict__ pBG, const float* __restrict__ pBT,
               const float* __restrict__ pBB, const float* __restrict__ pBW,
               const float* __restrict__ lam1, const float* __restrict__ lam2,
               const float* __restrict__ qd,  const float* __restrict__ rd,
               const float* __restrict__ pG1, const float* __restrict__ pG2,
               float* __restrict__ partial, int N, int Nt)
{
    const int lane = threadIdx.x;
    const int n = blockIdx.x * 64 + lane;
    const bool valid = (n < N);
    const int rowlen = Nt * 9;          // 576
    const int nchunk = Nt / 4;          // 16 chunks of 4 steps (36 floats = 9 float4)

    // ---- setup (wave-uniform scalars) ----
    const float bg = pBG[0], bt = pBT[0], bb = pBB[0], bw = pBW[0];
    float a[9], l2v[9], id[9], ad[9], ld[9];
    a[0] = 1.f; a[1] = lam1[0]; a[2] = lam1[1];
    a[3] = 1.f; a[4] = lam1[2]; a[5] = lam1[3];
    a[6] = 1.f; a[7] = lam1[4]; a[8] = lam1[5];
    l2v[0] = 1.f;
    #pragma unroll
    for (int i = 0; i < 8; ++i) l2v[i + 1] = lam2[i];
    float l2detD = 0.f;                              // log2(det D)
    #pragma unroll
    for (int o = 0; o < 9; ++o) {
        float dv = fabsf(rd[o]) + 1.0e-4f + 1.0e-5f; // R diag + jitter
        id[o] = 1.0f / dv;
        ad[o] = a[o] * id[o];
        ld[o] = l2v[o] * id[o];
        l2detD += flog2(dv);
    }
    const float q0 = fabsf(qd[0]) + 1e-4f, q1 = fabsf(qd[1]) + 1e-4f;
    const float q2 = fabsf(qd[2]) + 1e-4f, q3 = fabsf(qd[3]) + 1e-4f;
    const float g0 = a[0]*ad[0] + a[1]*ad[1] + a[2]*ad[2];   // A^T D^-1 A (diag)
    const float g1 = a[3]*ad[3] + a[4]*ad[4] + a[5]*ad[5];
    const float g2 = a[6]*ad[6] + a[7]*ad[7] + a[8]*ad[8];
    float h = 0.f;
    #pragma unroll
    for (int o = 0; o < 9; ++o) h += l2v[o] * ld[o];         // l2^T D^-1 l2
    const float pk0 = q0 / (1.f + q0 * g0);
    const float pk1 = q1 / (1.f + q1 * g1);
    const float pk2 = q2 / (1.f + q2 * g2);
    const float K12 = -0.5f * flog2((1.f + q0*g0) * (1.f + q1*g1) * (1.f + q2*g2));
    const float gam1 = pG1[0], w0 = pG2[0], w1 = pG2[1], w2 = pG2[2];
    const float CC = -0.5f * (l2detD + L2_2PI_9);    // per-step constant of ll_t (base 2)

    // ---- state ----
    float pf1 = 0.99f + EPSF, pf2 = 0.01f + EPSF;    // prob + EPS (linear)
    float se0 = 0.f, se1 = 0.f, se2 = 0.f;
    float P00 = 1000.f, P01 = 0.f, P02 = 0.f, P11 = 1000.f, P12 = 0.f, P22 = 1000.f;
    float sm2 = 0.f, sp2 = 1e-9f;
    float acc2 = 0.0f;                               // sum of (M2 + log2 ssum)

    const float* row = y + (size_t)(valid ? n : 0) * rowlen;

    float4 A[9], B[9];
    #pragma unroll
    for (int i = 0; i < 9; ++i) A[i] = *(const float4*)(row + i * 4);

    auto step4 = [&](const float4 (&buf)[9]) {
        #pragma unroll
        for (int s = 0; s < 4; ++s) {
            float yv[9];
            #pragma unroll
            for (int o = 0; o < 9; ++o) {
                const int idx = s * 9 + o, vno = idx >> 2, cm = idx & 3;
                yv[o] = (cm == 0) ? buf[vno].x : (cm == 1) ? buf[vno].y
                      : (cm == 2) ? buf[vno].z : buf[vno].w;
            }

            // HMM transition: direct sigmoid (linear factors, + EPS like reference)
            float logit = gam1 + w0 * se0 + w1 * se1 + w2 * se2;
            float esig = fexp2(-logit * L2E);
            float p11 = frcp(1.f + esig);
            float pf11 = p11 + EPSF;                 // p11 + EPS
            float pf21 = 1.f - p11 + EPSF;           // (1-p11) + EPS

            // ---------- branch 11 (r1->r1): one 3x3 inversion via M = I + S*G ----------
            float ep0 = bg * se0, ep1 = bt * se1, ep2 = bb * se2;
            float S00 = bg*bg*P00 + q0, S01 = bg*bt*P01, S02 = bg*bb*P02;
            float S11 = bt*bt*P11 + q1, S12 = bt*bb*P12, S22 = bb*bb*P22 + q2;
            float v0 = yv[0] - a[0]*ep0, v1 = yv[1] - a[1]*ep0, v2 = yv[2] - a[2]*ep0;
            float v3 = yv[3] - a[3]*ep1, v4 = yv[4] - a[4]*ep1, v5 = yv[5] - a[5]*ep1;
            float v6 = yv[6] - a[6]*ep2, v7 = yv[7] - a[7]*ep2, v8 = yv[8] - a[8]*ep2;
            float u0 = ad[0]*v0 + ad[1]*v1 + ad[2]*v2;
            float u1 = ad[3]*v3 + ad[4]*v4 + ad[5]*v5;
            float u2 = ad[6]*v6 + ad[7]*v7 + ad[8]*v8;
            float vdv = id[0]*v0*v0 + id[1]*v1*v1 + id[2]*v2*v2
                      + id[3]*v3*v3 + id[4]*v4*v4 + id[5]*v5*v5
                      + id[6]*v6*v6 + id[7]*v7*v7 + id[8]*v8*v8;
            // M = I + S*diag(g)  (det F11 = det D * det M; post-cov Ci = M^-1 S)
            float M00 = S00*g0 + 1.f, M01 = S01*g1,       M02 = S02*g2;
            float M10 = S01*g0,       M11 = S11*g1 + 1.f, M12 = S12*g2;
            float M20 = S02*g0,       M21 = S12*g1,       M22 = S22*g2 + 1.f;
            float adj00 = M11*M22 - M12*M21, adj01 = M02*M21 - M01*M22, adj02 = M01*M12 - M02*M11;
            float adj10 = M12*M20 - M10*M22, adj11 = M00*M22 - M02*M20, adj12 = M02*M10 - M00*M12;
            float adj20 = M10*M21 - M11*M20, adj21 = M01*M20 - M00*M21, adj22 = M00*M11 - M01*M10;
            float detM = M00*adj00 + M01*adj10 + M02*adj20;
            float iM = frcp(detM);
            // N = adj(M) * S  (overlaps the rcp); Ci = N * iM (symmetric)
            float N00 = adj00*S00 + adj01*S01 + adj02*S02;
            float N01 = adj00*S01 + adj01*S11 + adj02*S12;
            float N02 = adj00*S02 + adj01*S12 + adj02*S22;
            float N11 = adj10*S01 + adj11*S11 + adj12*S12;
            float N12 = adj10*S02 + adj11*S12 + adj12*S22;
            float N22 = adj20*S02 + adj21*S12 + adj22*S22;
            float Ci00 = N00*iM, Ci01 = N01*iM, Ci02 = N02*iM;
            float Ci11 = N11*iM, Ci12 = N12*iM, Ci22 = N22*iM;
            float t0 = Ci00*u0 + Ci01*u1 + Ci02*u2;
            float t1 = Ci01*u0 + Ci11*u1 + Ci12*u2;
            float t2 = Ci02*u0 + Ci12*u1 + Ci22*u2;
            float quad11 = vdv - (u0*t0 + u1*t1 + u2*t2);
            float n2_11 = -0.5f * fmaf(quad11, L2E, flog2(detM));
            float eu0 = ep0 + t0, eu1 = ep1 + t1, eu2 = ep2 + t2;

            // ---------- branch 12 (r2->r1): constant prior ----------
            float u120 = u0 + g0*ep0, u121 = u1 + g1*ep1, u122 = u2 + g2*ep2;
            float ydy = vdv + 2.f*(ep0*u0 + ep1*u1 + ep2*u2)
                      + g0*ep0*ep0 + g1*ep1*ep1 + g2*ep2*ep2;
            float quad12 = ydy - (pk0*u120*u120 + pk1*u121*u121 + pk2*u122*u122);
            float n2_12 = -0.5f * quad12 * L2E + K12;
            float f0 = pk0*u120, f1 = pk1*u121, f2 = pk2*u122;

            // ---------- branches 21/22 (-> r2): rank-1 Sherman-Morrison ----------
            float yl = ld[0]*yv[0] + ld[1]*yv[1] + ld[2]*yv[2] + ld[3]*yv[3] + ld[4]*yv[4]
                     + ld[5]*yv[5] + ld[6]*yv[6] + ld[7]*yv[7] + ld[8]*yv[8];
            float m21 = (se0 + se1 + se2) * (1.0f / 3.0f);
            float sP = P00 + P11 + P22 + 2.f*(P01 + P02 + P12);
            float pa = q3 + (1.0f / 9.0f) * sP;
            float m22 = bw * sm2;
            float pb = bw*bw*sp2 + q3;
            float u1a = yl - m21*h;
            float vda = ydy - m21*(2.f*yl - m21*h);
            float dena = 1.f + pa*h;  float idea = frcp(dena);
            float quad21 = vda - pa*u1a*u1a*idea;
            float n2_21 = -0.5f * fmaf(quad21, L2E, flog2(dena));
            float pua = pa*idea;
            float eua = m21 + pua*u1a;
            float u1b = yl - m22*h;
            float vdb = ydy - m22*(2.f*yl - m22*h);
            float denb = 1.f + pb*h;  float ideb = frcp(denb);
            float quad22 = vdb - pb*u1b*u1b*ideb;
            float n2_22 = -0.5f * fmaf(quad22, L2E, flog2(denb));
            float pub = pb*ideb;
            float eub = m22 + pub*u1b;

            // ---------- mixing (scaled-linear domain; exact vs reference) ----------
            float M2 = fmaxf(fmaxf(n2_11, n2_12), fmaxf(n2_21, n2_22));
            float w11 = pf1 * pf11 * fexp2(n2_11 - M2);
            float w21 = pf1 * pf21 * fexp2(n2_21 - M2);
            float w12 = pf2 * C12F * fexp2(n2_12 - M2);
            float w22 = pf2 * P22F * fexp2(n2_22 - M2);
            float ssum = w11 + w12 + w21 + w22;
            acc2 += M2 + flog2(ssum);
            float pr1n = w11 + w12, pr2n = w21 + w22;
            float den1 = pr1n + EPSF * ssum;
            float den2 = pr2n + EPSF * ssum;
            float inv1 = frcp(den1);
            float inv2 = frcp(den2);
            float W11 = w11 * inv1, W12 = w12 * inv1;
            float W21 = w21 * inv2, W22 = w22 * inv2;
            float issum = frcp(ssum);
            pf1 = pr1n * issum + EPSF;               // prob1 + EPS for next step
            pf2 = pr2n * issum + EPSF;

            // ---------- collapse regime 1 (3x3) ----------
            float ne0 = W11*eu0 + W12*f0;
            float ne1 = W11*eu1 + W12*f1;
            float ne2 = W11*eu2 + W12*f2;
            float da0 = eu0 - ne0, da1 = eu1 - ne1, da2 = eu2 - ne2;
            float db0 = f0 - ne0,  db1 = f1 - ne1,  db2 = f2 - ne2;
            P00 = W11*(Ci00 + da0*da0) + W12*(pk0 + db0*db0);
            P01 = W11*(Ci01 + da0*da1) + W12*(db0*db1);
            P02 = W11*(Ci02 + da0*da2) + W12*(db0*db2);
            P11 = W11*(Ci11 + da1*da1) + W12*(pk1 + db1*db1);
            P12 = W11*(Ci12 + da1*da2) + W12*(db1*db2);
            P22 = W11*(Ci22 + da2*da2) + W12*(pk2 + db2*db2);
            se0 = ne0; se1 = ne1; se2 = ne2;

            // ---------- collapse regime 2 (scalar) ----------
            float nm2 = W21*eua + W22*eub;
            float dc = eua - nm2, dd = eub - nm2;
            sp2 = W21*(pua + dc*dc) + W22*(pub + dd*dd);
            sm2 = nm2;
        }
    };

    // chunk pairs: compute A(c) while B(c+1) loads; compute B while A(c+2) loads
    for (int c = 0; c < nchunk; c += 2) {
        if (c + 1 < nchunk) {
            const float* p = row + (c + 1) * 36;
            #pragma unroll
            for (int i = 0; i < 9; ++i) B[i] = *(const float4*)(p + i * 4);
        }
        step4(A);
        if (c + 2 < nchunk) {
            const float* p = row + (c + 2) * 36;
            #pragma unroll
            for (int i = 0; i < 9; ++i) A[i] = *(const float4*)(p + i * 4);
        }
        step4(B);
    }

    // total ll in natural log: (acc2 + Nt*CC) * ln2
    float acc = valid ? (acc2 + (float)Nt * CC) * LN2 : 0.0f;
    #pragma unroll
    for (int off = 32; off; off >>= 1) acc += __shfl_down(acc, off, 64);
    if (lane == 0) partial[blockIdx.x] = acc;
}

__global__ __launch_bounds__(64)
void reduce_k(const float* __restrict__ part, float* __restrict__ out, int nb)
{
    float s = 0.f;
    for (int i = threadIdx.x; i < nb; i += 64) s += part[i];
    #pragma unroll
    for (int off = 32; off; off >>= 1) s += __shfl_down(s, off, 64);
    if (threadIdx.x == 0) out[0] = s;
}

extern "C" void kernel_launch(void* const* d_in, const int* in_sizes, int n_in,
                              void* d_out, int out_size, void* d_ws, size_t ws_size,
                              hipStream_t stream)
{
    const float* y    = (const float*)d_in[0];
    const float* pBG  = (const float*)d_in[1];
    const float* pBT  = (const float*)d_in[2];
    const float* pBB  = (const float*)d_in[3];
    const float* pBW  = (const float*)d_in[4];
    const float* lam1 = (const float*)d_in[5];
    const float* lam2 = (const float*)d_in[6];
    const float* qd   = (const float*)d_in[7];
    const float* rd   = (const float*)d_in[8];
    const float* pG1  = (const float*)d_in[9];
    const float* pG2  = (const float*)d_in[10];

    const int total = in_sizes[0];
    const int Nt = 64, O = 9;
    const int N = total / (Nt * O);
    const int blocks = (N + 63) / 64;

    float* partial = (float*)d_ws;
    kf_kernel<<<blocks, 64, 0, stream>>>(y, pBG, pBT, pBB, pBW, lam1, lam2,
                                         qd, rd, pG1, pG2, partial, N, Nt);
    reduce_k<<<1, 64, 0, stream>>>(partial, (float*)d_out, blocks);
}

// Round 6
// 127.406 us; speedup vs baseline: 1.5872x; 1.0887x over previous
//
#include <hip/hip_runtime.h>

// Regime-switching Kalman filter, structure-exploiting scalar form.
// One thread per series; register double-buffered 4-step chunks (9 float4);
// __launch_bounds__(64,1) so the prefetch buffers stay live (512-VGPR budget).
// This revision packs the element-parallel math into float2 ext-vectors so the
// backend emits v_pk_*_f32 (2 f32 per issue slot on CDNA), and replaces
// log2(det) in the branch densities with v_rsq_f32 folded into the mixing
// weights (algebraically identical, 3 fewer transcendentals in the chain).

typedef float v2f __attribute__((ext_vector_type(2)));

static __device__ __forceinline__ float frcp(float x)  { return __builtin_amdgcn_rcpf(x); }
static __device__ __forceinline__ float frsq(float x)  { return __builtin_amdgcn_rsqf(x); }
static __device__ __forceinline__ float fexp2(float x) { return __builtin_amdgcn_exp2f(x); }
static __device__ __forceinline__ float flog2(float x) { return __builtin_amdgcn_logf(x); }
static __device__ __forceinline__ v2f   splat(float s) { return (v2f){s, s}; }

#define EPSF   1e-9f
#define L2E    1.4426950408889634f    // log2(e)
#define LN2    0.6931471805599453f
#define L2_2PI_9 23.86346461225016f   // 9*log2(2*pi)
#define C12F   1.00001e-4f            // (1 - 0.9999) + 1e-9
#define P22F   0.99990001f            // 0.9999 + 1e-9
#define QK     (-0.5f * L2E)

__global__ __launch_bounds__(64, 1)
void kf_kernel(const float* __restrict__ y,      // y[n][t][o]
               const float* __restrict__ pBG, const float* __restrict__ pBT,
               const float* __restrict__ pBB, const float* __restrict__ pBW,
               const float* __restrict__ lam1, const float* __restrict__ lam2,
               const float* __restrict__ qd,  const float* __restrict__ rd,
               const float* __restrict__ pG1, const float* __restrict__ pG2,
               float* __restrict__ partial, int N, int Nt)
{
    const int lane = threadIdx.x;
    const int n = blockIdx.x * 64 + lane;
    const bool valid = (n < N);
    const int rowlen = Nt * 9;          // 576
    const int nchunk = Nt / 4;          // 16 chunks of 4 steps (36 floats = 9 float4)

    // ---- setup (wave-uniform scalars) ----
    const float bg = pBG[0], bt = pBT[0], bb = pBB[0], bw = pBW[0];
    float a[9], l2v[9], id[9], ld[9];
    a[0] = 1.f; a[1] = lam1[0]; a[2] = lam1[1];
    a[3] = 1.f; a[4] = lam1[2]; a[5] = lam1[3];
    a[6] = 1.f; a[7] = lam1[4]; a[8] = lam1[5];
    l2v[0] = 1.f;
    #pragma unroll
    for (int i = 0; i < 8; ++i) l2v[i + 1] = lam2[i];
    float l2detD = 0.f;                              // log2(det D)
    #pragma unroll
    for (int o = 0; o < 9; ++o) {
        float dv = fabsf(rd[o]) + 1.0e-4f + 1.0e-5f; // R diag + jitter
        id[o] = 1.0f / dv;
        ld[o] = l2v[o] * id[o];
        l2detD += flog2(dv);
    }
    const float q0 = fabsf(qd[0]) + 1e-4f, q1 = fabsf(qd[1]) + 1e-4f;
    const float q2 = fabsf(qd[2]) + 1e-4f, q3 = fabsf(qd[3]) + 1e-4f;
    const float g0 = a[0]*a[0]*id[0] + a[1]*a[1]*id[1] + a[2]*a[2]*id[2];  // A^T D^-1 A
    const float g1 = a[3]*a[3]*id[3] + a[4]*a[4]*id[4] + a[5]*a[5]*id[5];
    const float g2 = a[6]*a[6]*id[6] + a[7]*a[7]*id[7] + a[8]*a[8]*id[8];
    float h = 0.f;
    #pragma unroll
    for (int o = 0; o < 9; ++o) h += l2v[o] * ld[o];         // l2^T D^-1 l2
    const float pk0 = q0 / (1.f + q0 * g0);
    const float pk1 = q1 / (1.f + q1 * g1);
    const float pk2 = q2 / (1.f + q2 * g2);
    // det of branch-12 innovation folded into its linear prior factor:
    const float C12D = C12F * frsq((1.f + q0*g0) * (1.f + q1*g1) * (1.f + q2*g2));
    const float gam1 = pG1[0], w0 = pG2[0], w1 = pG2[1], w2 = pG2[2];
    const float CC = -0.5f * (l2detD + L2_2PI_9);    // per-step constant (base 2)

    // packed constants
    const v2f av01 = {a[0], a[1]}, av23 = {a[2], a[3]}, av45 = {a[4], a[5]}, av67 = {a[6], a[7]};
    const float a8 = a[8];
    const v2f idv01 = {id[0], id[1]}, idv23 = {id[2], id[3]}, idv45 = {id[4], id[5]}, idv67 = {id[6], id[7]};
    const float id8 = id[8];
    const v2f ldv01 = {ld[0], ld[1]}, ldv23 = {ld[2], ld[3]}, ldv45 = {ld[4], ld[5]}, ldv67 = {ld[6], ld[7]};
    const float ld8 = ld[8];
    const v2f cS0 = {bg*bg, bg*bt}, cS1 = {bg*bb, bt*bt}, cS2 = {bt*bb, bb*bb};
    const v2f qS0 = {q0, 0.f},  qS1 = {0.f, q1},  qS2 = {0.f, q2};
    const v2f pkv0 = {pk0, 0.f}, pkv1 = {0.f, pk1}, pkv2 = {0.f, pk2};
    const v2f bgt = {bg, bt};

    // ---- state ----
    float pf1 = 0.99f + EPSF, pf2 = 0.01f + EPSF;    // prob + EPS (linear)
    v2f se01 = {0.f, 0.f};  float se2 = 0.f;
    v2f Pv0 = {1000.f, 0.f};          // {P00,P01}
    v2f Pv1 = {0.f, 1000.f};          // {P02,P11}
    v2f Pv2 = {0.f, 1000.f};          // {P12,P22}
    float sm2 = 0.f, sp2 = 1e-9f;
    float acc2 = 0.0f;                               // sum of (Mq + log2 ssum)

    const float* row = y + (size_t)(valid ? n : 0) * rowlen;

    float4 A[9], B[9];
    #pragma unroll
    for (int i = 0; i < 9; ++i) A[i] = *(const float4*)(row + i * 4);

    auto step4 = [&](const float4 (&buf)[9]) {
        #pragma unroll
        for (int s = 0; s < 4; ++s) {
            float yv[9];
            #pragma unroll
            for (int o = 0; o < 9; ++o) {
                const int idx = s * 9 + o, vno = idx >> 2, cm = idx & 3;
                yv[o] = (cm == 0) ? buf[vno].x : (cm == 1) ? buf[vno].y
                      : (cm == 2) ? buf[vno].z : buf[vno].w;
            }
            const v2f yvv0 = {yv[0], yv[1]}, yvv1 = {yv[2], yv[3]};
            const v2f yvv2 = {yv[4], yv[5]}, yvv3 = {yv[6], yv[7]};
            const float yv8 = yv[8];

            const float se0 = se01.x, se1 = se01.y;
            // HMM transition
            float logit = gam1 + w0 * se0 + w1 * se1 + w2 * se2;
            float esig = fexp2(-logit * L2E);
            float p11 = frcp(1.f + esig);
            float pf11 = p11 + EPSF;
            float pf21 = 1.f - p11 + EPSF;

            // ---------- predictions (packed) ----------
            v2f ep01 = bgt * se01;               // {ep0,ep1}
            float ep0 = ep01.x, ep1 = ep01.y, ep2 = bb * se2;
            v2f Sv0 = cS0 * Pv0 + qS0;           // {S00,S01}
            v2f Sv1 = cS1 * Pv1 + qS1;           // {S02,S11}
            v2f Sv2 = cS2 * Pv2 + qS2;           // {S12,S22}
            float S00 = Sv0.x, S01 = Sv0.y, S02 = Sv1.x;
            float S11 = Sv1.y, S12 = Sv2.x, S22 = Sv2.y;

            // ---------- innovation (packed) ----------
            v2f vv0 = yvv0 - av01 * splat(ep0);
            v2f vv1 = yvv1 - av23 * ep01;        // obs2 uses ep0, obs3 uses ep1
            v2f vv2 = yvv2 - av45 * splat(ep1);
            v2f vv3 = yvv3 - av67 * splat(ep2);
            float v8 = yv8 - a8 * ep2;
            v2f w0v = idv01 * vv0, w1v = idv23 * vv1, w2v = idv45 * vv2, w3v = idv67 * vv3;
            float w8 = id8 * v8;
            v2f pA = av01 * w0v, pB = av23 * w1v, pC = av45 * w2v, pD = av67 * w3v;
            float u0 = pA.x + pA.y + pB.x;
            float u1 = pB.y + pC.x + pC.y;
            float u2 = pD.x + pD.y + a8 * w8;
            v2f vds = vv0 * w0v + vv1 * w1v + vv2 * w2v + vv3 * w3v;
            float vdv = vds.x + vds.y + v8 * w8;
            v2f ylv = ldv01 * yvv0 + ldv23 * yvv1 + ldv45 * yvv2 + ldv67 * yvv3;
            float yl = ylv.x + ylv.y + ld8 * yv8;

            // ---------- branch 11: one 3x3 inversion via M = I + S*G ----------
            float M00 = S00*g0 + 1.f, M01 = S01*g1,       M02 = S02*g2;
            float M10 = S01*g0,       M11 = S11*g1 + 1.f, M12 = S12*g2;
            float M20 = S02*g0,       M21 = S12*g1,       M22 = S22*g2 + 1.f;
            float adj00 = M11*M22 - M12*M21, adj01 = M02*M21 - M01*M22, adj02 = M01*M12 - M02*M11;
            float adj10 = M12*M20 - M10*M22, adj11 = M00*M22 - M02*M20, adj12 = M02*M10 - M00*M12;
            float adj20 = M10*M21 - M11*M20, adj21 = M01*M20 - M00*M21, adj22 = M00*M11 - M01*M10;
            float detM = M00*adj00 + M01*adj10 + M02*adj20;
            float iM = frcp(detM);
            float N00 = adj00*S00 + adj01*S01 + adj02*S02;
            float N01 = adj00*S01 + adj01*S11 + adj02*S12;
            float N02 = adj00*S02 + adj01*S12 + adj02*S22;
            float N11 = adj10*S01 + adj11*S11 + adj12*S12;
            float N12 = adj10*S02 + adj11*S12 + adj12*S22;
            float N22 = adj20*S02 + adj21*S12 + adj22*S22;
            v2f Civ0 = (v2f){N00, N01} * splat(iM);   // {Ci00,Ci01}
            v2f Civ1 = (v2f){N02, N11} * splat(iM);   // {Ci02,Ci11}
            v2f Civ2 = (v2f){N12, N22} * splat(iM);   // {Ci12,Ci22}
            float Ci00 = Civ0.x, Ci01 = Civ0.y, Ci02 = Civ1.x;
            float Ci11 = Civ1.y, Ci12 = Civ2.x, Ci22 = Civ2.y;
            float t0 = Ci00*u0 + Ci01*u1 + Ci02*u2;
            float t1 = Ci01*u0 + Ci11*u1 + Ci12*u2;
            float t2 = Ci02*u0 + Ci12*u1 + Ci22*u2;
            float quad11 = vdv - (u0*t0 + u1*t1 + u2*t2);
            v2f euv01 = ep01 + (v2f){t0, t1};
            float eu2 = ep2 + t2;

            // ---------- branch 12: constant prior ----------
            float u120 = u0 + g0*ep0, u121 = u1 + g1*ep1, u122 = u2 + g2*ep2;
            float ydy = vdv + 2.f*(ep0*u0 + ep1*u1 + ep2*u2)
                      + g0*ep0*ep0 + g1*ep1*ep1 + g2*ep2*ep2;
            float quad12 = ydy - (pk0*u120*u120 + pk1*u121*u121 + pk2*u122*u122);
            v2f f01 = (v2f){pk0*u120, pk1*u121};
            float f2 = pk2*u122;

            // ---------- branches 21/22: twin-packed rank-1 Sherman-Morrison ----------
            float m21 = (se0 + se1 + se2) * (1.0f / 3.0f);
            float sP = Pv0.x + Pv1.y + Pv2.y + 2.f*(Pv0.y + Pv1.x + Pv2.x);
            v2f m2v = {m21, bw * sm2};
            v2f pv  = {q3 + sP * (1.0f / 9.0f), bw*bw*sp2 + q3};
            v2f u1v = splat(yl) - m2v * splat(h);
            v2f vdav = splat(ydy) - m2v * (splat(2.f * yl) - m2v * splat(h));
            v2f denv = splat(1.f) + pv * splat(h);
            v2f idev = {frcp(denv.x), frcp(denv.y)};
            v2f puv = pv * idev;                      // posterior variances
            v2f quadv = vdav - puv * u1v * u1v;
            v2f euv = m2v + puv * u1v;

            // ---------- mixing (scaled-linear; dets via rsq folded into weights) ----------
            float q11e = QK * quad11, q12e = QK * quad12;
            v2f  q2v  = splat(QK) * quadv;            // {q21,q22}
            float Mq = fmaxf(fmaxf(q11e, q12e), fmaxf(q2v.x, q2v.y));
            float w11 = pf1 * pf11 * frsq(detM) * fexp2(q11e - Mq);
            float w12 = pf2 * C12D * fexp2(q12e - Mq);
            float w21 = pf1 * pf21 * frsq(denv.x) * fexp2(q2v.x - Mq);
            float w22 = pf2 * P22F * frsq(denv.y) * fexp2(q2v.y - Mq);
            float ssum = w11 + w12 + w21 + w22;
            acc2 += Mq + flog2(ssum);
            float pr1n = w11 + w12, pr2n = w21 + w22;
            float den1 = pr1n + EPSF * ssum;
            float den2 = pr2n + EPSF * ssum;
            float inv1 = frcp(den1), inv2 = frcp(den2);
            float W11 = w11 * inv1, W12 = w12 * inv1;
            float W21 = w21 * inv2, W22 = w22 * inv2;
            float issum = frcp(ssum);
            pf1 = pr1n * issum + EPSF;
            pf2 = pr2n * issum + EPSF;

            // ---------- collapse regime 1 (packed) ----------
            v2f nev01 = splat(W11) * euv01 + splat(W12) * f01;
            float ne2 = W11 * eu2 + W12 * f2;
            v2f dav01 = euv01 - nev01;  float da2 = eu2 - ne2;
            v2f dbv01 = f01 - nev01;    float db2 = f2 - ne2;
            float da0 = dav01.x, da1 = dav01.y, db0 = dbv01.x, db1 = dbv01.y;
            Pv0 = splat(W11) * (Civ0 + splat(da0) * dav01)
                + splat(W12) * (pkv0 + splat(db0) * dbv01);
            Pv1 = splat(W11) * (Civ1 + dav01 * (v2f){da2, da1})
                + splat(W12) * (pkv1 + dbv01 * (v2f){db2, db1});
            Pv2 = splat(W11) * (Civ2 + (v2f){da1, da2} * splat(da2))
                + splat(W12) * (pkv2 + (v2f){db1, db2} * splat(db2));
            se01 = nev01; se2 = ne2;

            // ---------- collapse regime 2 (scalar) ----------
            float nm2 = W21 * euv.x + W22 * euv.y;
            float dc = euv.x - nm2, dd = euv.y - nm2;
            sp2 = W21 * (puv.x + dc*dc) + W22 * (puv.y + dd*dd);
            sm2 = nm2;
        }
    };

    // chunk pairs: compute A(c) while B(c+1) loads; compute B while A(c+2) loads
    for (int c = 0; c < nchunk; c += 2) {
        if (c + 1 < nchunk) {
            const float* p = row + (c + 1) * 36;
            #pragma unroll
            for (int i = 0; i < 9; ++i) B[i] = *(const float4*)(p + i * 4);
        }
        step4(A);
        if (c + 2 < nchunk) {
            const float* p = row + (c + 2) * 36;
            #pragma unroll
            for (int i = 0; i < 9; ++i) A[i] = *(const float4*)(p + i * 4);
        }
        step4(B);
    }

    // total ll in natural log: (acc2 + Nt*CC) * ln2
    float acc = valid ? (acc2 + (float)Nt * CC) * LN2 : 0.0f;
    #pragma unroll
    for (int off = 32; off; off >>= 1) acc += __shfl_down(acc, off, 64);
    if (lane == 0) partial[blockIdx.x] = acc;
}

__global__ __launch_bounds__(64)
void reduce_k(const float* __restrict__ part, float* __restrict__ out, int nb)
{
    float s = 0.f;
    for (int i = threadIdx.x; i < nb; i += 64) s += part[i];
    #pragma unroll
    for (int off = 32; off; off >>= 1) s += __shfl_down(s, off, 64);
    if (threadIdx.x == 0) out[0] = s;
}

extern "C" void kernel_launch(void* const* d_in, const int* in_sizes, int n_in,
                              void* d_out, int out_size, void* d_ws, size_t ws_size,
                              hipStream_t stream)
{
    const float* y    = (const float*)d_in[0];
    const float* pBG  = (const float*)d_in[1];
    const float* pBT  = (const float*)d_in[2];
    const float* pBB  = (const float*)d_in[3];
    const float* pBW  = (const float*)d_in[4];
    const float* lam1 = (const float*)d_in[5];
    const float* lam2 = (const float*)d_in[6];
    const float* qd   = (const float*)d_in[7];
    const float* rd   = (const float*)d_in[8];
    const float* pG1  = (const float*)d_in[9];
    const float* pG2  = (const float*)d_in[10];

    const int total = in_sizes[0];
    const int Nt = 64, O = 9;
    const int N = total / (Nt * O);
    const int blocks = (N + 63) / 64;

    float* partial = (float*)d_ws;
    kf_kernel<<<blocks, 64, 0, stream>>>(y, pBG, pBT, pBB, pBW, lam1, lam2,
                                         qd, rd, pG1, pG2, partial, N, Nt);
    reduce_k<<<1, 64, 0, stream>>>(partial, (float*)d_out, blocks);
}